// Round 4
// baseline (434.281 us; speedup 1.0000x reference)
//
#include <hip/hip_runtime.h>

#define N_NODES 10000
#define EDGES   160000
#define BATCH   8
#define TT      12
#define HID     64
#define EPAD    230000   // 160000 + 10000*7 worst-case pad-to-8

// ---------------- CSR build ----------------

__global__ __launch_bounds__(256) void k_deg_hist(const int* __restrict__ ei,
                                                  const float* __restrict__ ew,
                                                  float* __restrict__ deg,
                                                  int* __restrict__ cnt) {
  int g = blockIdx.x * 256 + threadIdx.x;
  if (g < EDGES) {
    int d = ei[EDGES + g];
    atomicAdd(&deg[d], ew[g]);
    atomicAdd(&cnt[d], 1);
  }
}

__global__ __launch_bounds__(256) void k_dinv(const float* __restrict__ deg,
                                              float* __restrict__ dinv) {
  int g = blockIdx.x * 256 + threadIdx.x;
  if (g < N_NODES) dinv[g] = 1.0f / sqrtf(deg[g] + 1.0f);  // +1 = self-loop weight
}

// prefix scan of per-node counts PADDED UP TO MULTIPLE OF 8
__global__ __launch_bounds__(1024) void k_scan(const int* __restrict__ cnt,
                                               int* __restrict__ row_ptr,
                                               int* __restrict__ cursor) {
  __shared__ int part[1024];
  int tid = threadIdx.x;
  int base = tid * 10;
  int local[10];
  int s = 0;
  #pragma unroll
  for (int j = 0; j < 10; j++) {
    int idx = base + j;
    int v = (idx < N_NODES) ? cnt[idx] : 0;
    v = (v + 7) & ~7;              // pad each node's list to multiple of 8
    local[j] = s;
    s += v;
  }
  part[tid] = s;
  __syncthreads();
  for (int off = 1; off < 1024; off <<= 1) {
    int v = (tid >= off) ? part[tid - off] : 0;
    __syncthreads();
    part[tid] += v;
    __syncthreads();
  }
  int pre = (tid > 0) ? part[tid - 1] : 0;
  #pragma unroll
  for (int j = 0; j < 10; j++) {
    int idx = base + j;
    if (idx < N_NODES) {
      int rpv = pre + local[j];
      row_ptr[idx] = rpv;
      cursor[idx]  = rpv;
    }
  }
  if (tid == 0) row_ptr[N_NODES] = part[1023];
}

__global__ __launch_bounds__(256) void k_fill(const int* __restrict__ ei,
                                              const float* __restrict__ ew,
                                              const float* __restrict__ dinv,
                                              int* __restrict__ cursor,
                                              int* __restrict__ csrc,
                                              float* __restrict__ cnorm) {
  int g = blockIdx.x * 256 + threadIdx.x;
  if (g < EDGES) {
    int s = ei[g], d = ei[EDGES + g];
    int slot = atomicAdd(&cursor[d], 1);
    csrc[slot]  = s;
    cnorm[slot] = dinv[s] * ew[g] * dinv[d];
  }
}

// fill pad slots (cursor[n]..rp[n+1]) with src=0, w=0
__global__ __launch_bounds__(256) void k_padfill(const int* __restrict__ rp,
                                                 const int* __restrict__ cursor,
                                                 int* __restrict__ csrc,
                                                 float* __restrict__ cnorm) {
  int n = blockIdx.x * 256 + threadIdx.x;
  if (n >= N_NODES) return;
  int e = cursor[n], e1 = rp[n + 1];
  for (; e < e1; e++) { csrc[e] = 0; cnorm[e] = 0.0f; }
}

// pack conv weights:
//  p1c [192][128]: row kk: t3=kk>>6, i=kk&63; col: half=col>>6 (t'=10+half), o=col&63
//  p2c [128][64]:  row kk: g=kk>>6 (t1 half), i=kk&63
//  pb1 [128] = tc1_b duplicated
__global__ __launch_bounds__(256) void k_pack(const float* __restrict__ tc1w,
                                              const float* __restrict__ tc2w,
                                              const float* __restrict__ tc1b,
                                              float* __restrict__ p1c,
                                              float* __restrict__ p2c,
                                              float* __restrict__ pb1) {
  int g = blockIdx.x * 256 + threadIdx.x;
  if (g < 24576) {
    int kk = g >> 7, col = g & 127;
    int t3 = kk >> 6, i = kk & 63;
    int half = col >> 6, o = col & 63;
    float v;
    if (half == 0) v = tc1w[o * 192 + i * 3 + t3];
    else           v = (t3 == 0) ? 0.0f : tc1w[o * 192 + i * 3 + (t3 - 1)];
    p1c[g] = v;
  } else if (g < 24576 + 8192) {
    int r = g - 24576;
    int kk = r >> 6, o = r & 63;
    int gk = kk >> 6, i = kk & 63;
    p2c[r] = tc2w[o * 192 + i * 3 + gk];
  } else if (g < 24576 + 8192 + 128) {
    int r = g - 24576 - 8192;
    pb1[r] = tc1b[r & 63];
  }
}

// ---------------- GCN layer 1: fused agg(X) @ W1 + b1, relu -> h1[b][n][t3*64+c] ----------------

__global__ __launch_bounds__(256) void k_aggg1(const float* __restrict__ X,
                                               const float* __restrict__ dinv,
                                               const int* __restrict__ rp,
                                               const int* __restrict__ csrc,
                                               const float* __restrict__ cnorm,
                                               const float* __restrict__ W1,
                                               const float* __restrict__ b1,
                                               float* __restrict__ h1) {
  int b = blockIdx.x & 7;                    // batch -> XCD affinity
  int grp = blockIdx.x >> 3;                 // 0..2499
  int n = grp * 4 + (threadIdx.x >> 6);
  int lane = threadIdx.x & 63;
  const float2* x0 = (const float2*)(X + (size_t)(b * TT + 9)  * N_NODES * 2);
  const float2* x1 = (const float2*)(X + (size_t)(b * TT + 10) * N_NODES * 2);
  const float2* x2 = (const float2*)(X + (size_t)(b * TT + 11) * N_NODES * 2);
  float a0x = 0.f, a0y = 0.f, a1x = 0.f, a1y = 0.f, a2x = 0.f, a2y = 0.f;
  int e0 = rp[n], e1 = rp[n + 1];
  for (int idx = e0 + lane; idx < e1; idx += 64) {
    float w = cnorm[idx];
    int s = csrc[idx];
    float2 s0 = x0[s], s1 = x1[s], s2v = x2[s];
    a0x += w * s0.x;  a0y += w * s0.y;
    a1x += w * s1.x;  a1y += w * s1.y;
    a2x += w * s2v.x; a2y += w * s2v.y;
  }
  if (lane == 0) {  // self-loop term
    float di = dinv[n];
    float sd = di * di;
    float2 v0 = x0[n], v1 = x1[n], v2 = x2[n];
    a0x += sd * v0.x; a0y += sd * v0.y;
    a1x += sd * v1.x; a1y += sd * v1.y;
    a2x += sd * v2.x; a2y += sd * v2.y;
  }
  #pragma unroll
  for (int off = 32; off > 0; off >>= 1) {
    a0x += __shfl_xor(a0x, off, 64);
    a0y += __shfl_xor(a0y, off, 64);
    a1x += __shfl_xor(a1x, off, 64);
    a1y += __shfl_xor(a1y, off, 64);
    a2x += __shfl_xor(a2x, off, 64);
    a2y += __shfl_xor(a2y, off, 64);
  }
  int c = lane;
  float w0 = W1[c], w1 = W1[64 + c], bc = b1[c];
  size_t ob = ((size_t)(b * N_NODES + n)) * 192 + c;
  h1[ob]       = fmaxf(a0x * w0 + a0y * w1 + bc, 0.0f);
  h1[ob + 64]  = fmaxf(a1x * w0 + a1y * w1 + bc, 0.0f);
  h1[ob + 128] = fmaxf(a2x * w0 + a2y * w1 + bc, 0.0f);
}

// ---------------- GCN layer 2 aggregation: t3-sliced (L2-resident) + 4-edge float4 groups ----
// wave per (b,t3,n): sub = lane>>4 picks one of 4 edges per group; q = lane&15 picks the
// 16B chunk of the 256B row. One global_load_dwordx4 fetches 4 edges' rows (1 KB).
__global__ __launch_bounds__(256) void k_agg1t4(const float* __restrict__ h1,
                                                const float* __restrict__ dinv,
                                                const int* __restrict__ rp,
                                                const int* __restrict__ csrc,
                                                const float* __restrict__ cnorm,
                                                float* __restrict__ ah) {
  int b = blockIdx.x & 7;
  int r = blockIdx.x >> 3;                   // 0..7499
  int t3 = r / 2500;
  int grp = r % 2500;
  int n = grp * 4 + (threadIdx.x >> 6);
  int lane = threadIdx.x & 63;
  int sub = lane >> 4;
  int q = lane & 15;
  const char* plane = (const char*)(h1 + (size_t)b * N_NODES * 192 + t3 * 64);
  int qoff = q * 16;
  float ax = 0.f, ay = 0.f, az = 0.f, aw = 0.f;
  int e0 = rp[n], e1 = rp[n + 1];
  for (int base = e0; base < e1; base += 64) {
    int idx = base + lane;
    int ic = (idx < e1) ? idx : e0;
    int   sv = csrc[ic];
    int   wv = ((const int*)cnorm)[ic];
    int m = e1 - base; if (m > 64) m = 64;   // multiple of 8
    int perm = sub * 4;                      // byte addr of source lane (4g+sub)
    int ng = m >> 2;                         // even
    #pragma unroll 2
    for (int g2 = 0; g2 < ng; g2++) {
      int   sj = __builtin_amdgcn_ds_bpermute(perm, sv);
      float wj = __int_as_float(__builtin_amdgcn_ds_bpermute(perm, wv));
      int voff = __mul24(sj, 768) + qoff;
      float4 hv = *(const float4*)(plane + voff);
      ax += wj * hv.x;
      ay += wj * hv.y;
      az += wj * hv.z;
      aw += wj * hv.w;
      perm += 16;
    }
  }
  // reduce across the 4 sub-groups
  ax += __shfl_xor(ax, 16, 64); ay += __shfl_xor(ay, 16, 64);
  az += __shfl_xor(az, 16, 64); aw += __shfl_xor(aw, 16, 64);
  ax += __shfl_xor(ax, 32, 64); ay += __shfl_xor(ay, 32, 64);
  az += __shfl_xor(az, 32, 64); aw += __shfl_xor(aw, 32, 64);
  if (sub == 0) {
    float di = dinv[n];
    float s2 = di * di;
    float4 self = *(const float4*)(plane + __mul24(n, 768) + qoff);
    float4 o;
    o.x = ax + s2 * self.x;
    o.y = ay + s2 * self.y;
    o.z = az + s2 * self.z;
    o.w = aw + s2 * self.w;
    *(float4*)((char*)ah + (((size_t)(b * N_NODES + n)) * 192 + t3 * 64) * 4 + qoff) = o;
  }
}

// ---------------- fused epilogue: W2-GEMM + conv1 + conv2 + out, per 64-node block -------
// sp (192x64) and t1 (64x128) never touch HBM.
__global__ __launch_bounds__(256, 2) void k_fused(const float* __restrict__ ah,
                                                  const float* __restrict__ W2,
                                                  const float* __restrict__ b2,
                                                  const float* __restrict__ p1c,
                                                  const float* __restrict__ pb1,
                                                  const float* __restrict__ p2c,
                                                  const float* __restrict__ tc2b,
                                                  const float* __restrict__ ow,
                                                  const float* __restrict__ obp,
                                                  float* __restrict__ out) {
  __shared__ __align__(16) float As[16 * 192];   // 12 KB, transposed [k][m]
  __shared__ __align__(16) float Ws[16 * 128];   // 8 KB, shared weight-chunk buffer
  __shared__ __align__(16) float spL[64 * 193];  // 49.4 KB, node-major [64][193-pad]
  __shared__ __align__(16) float t1L[64 * 129];  // 33 KB
  int tid = threadIdx.x;
  size_t nodeBase = (size_t)blockIdx.x * 64;
  const float* A = ah + nodeBase * 192;          // 192 rows x 64

  // ---- phase 1: sp = relu(A @ W2 + b2), M=192 N=64 K=64 -> spL
  {
    int ty = tid >> 3, tx = tid & 7;             // 32 x 8, microtile 6x8
    float acc[6][8] = {{0.f}};
    for (int k0 = 0; k0 < 64; k0 += 16) {
      #pragma unroll
      for (int rep = 0; rep < 3; rep++) {
        int idx = rep * 256 + tid;               // 0..767 float4s
        int row = idx >> 2, qd = idx & 3;
        float4 v = *(const float4*)(A + row * 64 + k0 + 4 * qd);
        As[(4 * qd + 0) * 192 + row] = v.x;
        As[(4 * qd + 1) * 192 + row] = v.y;
        As[(4 * qd + 2) * 192 + row] = v.z;
        As[(4 * qd + 3) * 192 + row] = v.w;
      }
      {
        int rr = tid >> 4, c4 = (tid & 15) * 4;  // 16x64 chunk of W2
        *(float4*)&Ws[rr * 64 + c4] = *(const float4*)(W2 + (k0 + rr) * 64 + c4);
      }
      __syncthreads();
      #pragma unroll
      for (int k = 0; k < 16; k++) {
        float a[6];
        #pragma unroll
        for (int i = 0; i < 6; i++) a[i] = As[k * 192 + 6 * ty + i];
        float4 w0 = *(const float4*)&Ws[k * 64 + 8 * tx];
        float4 w1 = *(const float4*)&Ws[k * 64 + 8 * tx + 4];
        float w[8] = {w0.x, w0.y, w0.z, w0.w, w1.x, w1.y, w1.z, w1.w};
        #pragma unroll
        for (int i = 0; i < 6; i++)
          #pragma unroll
          for (int j = 0; j < 8; j++)
            acc[i][j] += a[i] * w[j];
      }
      __syncthreads();
    }
    float bb[8];
    #pragma unroll
    for (int j = 0; j < 8; j++) bb[j] = b2[8 * tx + j];
    #pragma unroll
    for (int i = 0; i < 6; i++) {
      int m = 6 * ty + i;
      int basei = 64 * m + m / 3;                // == (m/3)*193 + (m%3)*64
      #pragma unroll
      for (int j = 0; j < 8; j++)
        spL[basei + 8 * tx + j] = fmaxf(acc[i][j] + bb[j], 0.0f);
    }
  }
  __syncthreads();

  // ---- phase 2: t1 = relu(sp_node[64x192] @ p1c[192x128] + pb1) -> t1L
  {
    int ty = tid >> 4, tx = tid & 15;            // 16 x 16, microtile 4x8
    float acc[4][8] = {{0.f}};
    for (int k0 = 0; k0 < 192; k0 += 16) {
      #pragma unroll
      for (int rep = 0; rep < 2; rep++) {
        int f = rep * 256 + tid;                 // 512 float4s = 16x128
        int rr = f >> 5, c4 = (f & 31) * 4;
        *(float4*)&Ws[rr * 128 + c4] = *(const float4*)(p1c + (k0 + rr) * 128 + c4);
      }
      __syncthreads();
      #pragma unroll
      for (int k = 0; k < 16; k++) {
        float a[4];
        #pragma unroll
        for (int i = 0; i < 4; i++) a[i] = spL[(4 * ty + i) * 193 + k0 + k];
        float4 w0 = *(const float4*)&Ws[k * 128 + 8 * tx];
        float4 w1 = *(const float4*)&Ws[k * 128 + 8 * tx + 4];
        float w[8] = {w0.x, w0.y, w0.z, w0.w, w1.x, w1.y, w1.z, w1.w};
        #pragma unroll
        for (int i = 0; i < 4; i++)
          #pragma unroll
          for (int j = 0; j < 8; j++)
            acc[i][j] += a[i] * w[j];
      }
      __syncthreads();
    }
    float bb[8];
    #pragma unroll
    for (int j = 0; j < 8; j++) bb[j] = pb1[8 * tx + j];
    #pragma unroll
    for (int i = 0; i < 4; i++)
      #pragma unroll
      for (int j = 0; j < 8; j++)
        t1L[(4 * ty + i) * 129 + 8 * tx + j] = fmaxf(acc[i][j] + bb[j], 0.0f);
  }
  __syncthreads();

  // ---- phase 3: last = relu(t1[64x128] @ p2c[128x64] + tc2b); out = last . ow + ob
  {
    int ty = tid >> 4, tx = tid & 15;            // rows 4ty+i, cols 4tx+j
    float acc[4][4] = {{0.f}};
    for (int k0 = 0; k0 < 128; k0 += 16) {
      {
        int rr = tid >> 4, c4 = (tid & 15) * 4;  // 16x64 chunk
        *(float4*)&Ws[rr * 64 + c4] = *(const float4*)(p2c + (k0 + rr) * 64 + c4);
      }
      __syncthreads();
      #pragma unroll
      for (int k = 0; k < 16; k++) {
        float a[4];
        #pragma unroll
        for (int i = 0; i < 4; i++) a[i] = t1L[(4 * ty + i) * 129 + k0 + k];
        float4 w = *(const float4*)&Ws[k * 64 + 4 * tx];
        #pragma unroll
        for (int i = 0; i < 4; i++) {
          acc[i][0] += a[i] * w.x;
          acc[i][1] += a[i] * w.y;
          acc[i][2] += a[i] * w.z;
          acc[i][3] += a[i] * w.w;
        }
      }
      __syncthreads();
    }
    float4 bb = *(const float4*)(tc2b + 4 * tx);
    float4 o4 = *(const float4*)(ow + 4 * tx);
    float obv = obp[0];
    #pragma unroll
    for (int i = 0; i < 4; i++) {
      float v = fmaxf(acc[i][0] + bb.x, 0.0f) * o4.x
              + fmaxf(acc[i][1] + bb.y, 0.0f) * o4.y
              + fmaxf(acc[i][2] + bb.z, 0.0f) * o4.z
              + fmaxf(acc[i][3] + bb.w, 0.0f) * o4.w;
      v += __shfl_xor(v, 1, 64);
      v += __shfl_xor(v, 2, 64);
      v += __shfl_xor(v, 4, 64);
      v += __shfl_xor(v, 8, 64);
      if (tx == 0) out[nodeBase + 4 * ty + i] = v + obv;
    }
  }
}

// ---------------- launch ----------------

extern "C" void kernel_launch(void* const* d_in, const int* in_sizes, int n_in,
                              void* d_out, int out_size, void* d_ws, size_t ws_size,
                              hipStream_t stream) {
  const float* X    = (const float*)d_in[0];
  const int*   EI   = (const int*)  d_in[1];
  const float* EW   = (const float*)d_in[2];
  const float* W1   = (const float*)d_in[3];
  const float* B1   = (const float*)d_in[4];
  const float* W2   = (const float*)d_in[5];
  const float* B2   = (const float*)d_in[6];
  const float* TC1W = (const float*)d_in[7];
  const float* TC1B = (const float*)d_in[8];
  const float* TC2W = (const float*)d_in[9];
  const float* TC2B = (const float*)d_in[10];
  const float* OW   = (const float*)d_in[11];
  const float* OB   = (const float*)d_in[12];
  float* out = (float*)d_out;

  char* base = (char*)d_ws;
  size_t off = 0;
  auto alloc = [&](size_t bytes) -> char* {
    char* p = base + off;
    off += (bytes + 255) & ~(size_t)255;
    return p;
  };
  float* deg   = (float*)alloc(N_NODES * 4);
  float* dinv  = (float*)alloc(N_NODES * 4);
  int*   cnt   = (int*)  alloc(N_NODES * 4);
  int*   rp    = (int*)  alloc((N_NODES + 1) * 4);
  int*   cur   = (int*)  alloc(N_NODES * 4);
  int*   csrc  = (int*)  alloc(EPAD * 4);
  float* cnorm = (float*)alloc(EPAD * 4);
  float* p1c   = (float*)alloc(192 * 128 * 4);
  float* p2c   = (float*)alloc(128 * 64 * 4);
  float* pb1   = (float*)alloc(128 * 4);
  const size_t BIG = (size_t)80000 * 192;
  float* h1 = (float*)alloc(BIG * 4);
  float* ah = (float*)alloc(BIG * 4);

  hipMemsetAsync(deg, 0, N_NODES * 4, stream);
  hipMemsetAsync(cnt, 0, N_NODES * 4, stream);
  k_deg_hist<<<625, 256, 0, stream>>>(EI, EW, deg, cnt);
  k_dinv<<<40, 256, 0, stream>>>(deg, dinv);
  k_scan<<<1, 1024, 0, stream>>>(cnt, rp, cur);
  k_fill<<<625, 256, 0, stream>>>(EI, EW, dinv, cur, csrc, cnorm);
  k_padfill<<<40, 256, 0, stream>>>(rp, cur, csrc, cnorm);
  k_pack<<<129, 256, 0, stream>>>(TC1W, TC2W, TC1B, p1c, p2c, pb1);

  // layer 1 (agg + W1 + relu), t=9..11 fused
  k_aggg1<<<20000, 256, 0, stream>>>(X, dinv, rp, csrc, cnorm, W1, B1, h1);
  // layer 2 aggregation, t3-sliced, 4-edge vector gather
  k_agg1t4<<<60000, 256, 0, stream>>>(h1, dinv, rp, csrc, cnorm, ah);
  // fused W2-GEMM + conv1 + conv2 + out
  k_fused<<<1250, 256, 0, stream>>>(ah, W2, B2, p1c, pb1, p2c, TC2B, OW, OB, out);
}

// Round 5
// 369.258 us; speedup vs baseline: 1.1761x; 1.1761x over previous
//
#include <hip/hip_runtime.h>

#define N_NODES 10000
#define EDGES   160000
#define BATCH   8
#define TT      12
#define HID     64
#define EPAD    230000   // 160000 + 10000*7 worst-case pad-to-8

// ---------------- CSR build ----------------

__global__ __launch_bounds__(256) void k_deg_hist(const int* __restrict__ ei,
                                                  const float* __restrict__ ew,
                                                  float* __restrict__ deg,
                                                  int* __restrict__ cnt) {
  int g = blockIdx.x * 256 + threadIdx.x;
  if (g < EDGES) {
    int d = ei[EDGES + g];
    atomicAdd(&deg[d], ew[g]);
    atomicAdd(&cnt[d], 1);
  }
}

__global__ __launch_bounds__(256) void k_dinv(const float* __restrict__ deg,
                                              float* __restrict__ dinv) {
  int g = blockIdx.x * 256 + threadIdx.x;
  if (g < N_NODES) dinv[g] = 1.0f / sqrtf(deg[g] + 1.0f);  // +1 = self-loop weight
}

// prefix scan of per-node counts PADDED UP TO MULTIPLE OF 8
__global__ __launch_bounds__(1024) void k_scan(const int* __restrict__ cnt,
                                               int* __restrict__ row_ptr,
                                               int* __restrict__ cursor) {
  __shared__ int part[1024];
  int tid = threadIdx.x;
  int base = tid * 10;
  int local[10];
  int s = 0;
  #pragma unroll
  for (int j = 0; j < 10; j++) {
    int idx = base + j;
    int v = (idx < N_NODES) ? cnt[idx] : 0;
    v = (v + 7) & ~7;              // pad each node's list to multiple of 8
    local[j] = s;
    s += v;
  }
  part[tid] = s;
  __syncthreads();
  for (int off = 1; off < 1024; off <<= 1) {
    int v = (tid >= off) ? part[tid - off] : 0;
    __syncthreads();
    part[tid] += v;
    __syncthreads();
  }
  int pre = (tid > 0) ? part[tid - 1] : 0;
  #pragma unroll
  for (int j = 0; j < 10; j++) {
    int idx = base + j;
    if (idx < N_NODES) {
      int rpv = pre + local[j];
      row_ptr[idx] = rpv;
      cursor[idx]  = rpv;
    }
  }
  if (tid == 0) row_ptr[N_NODES] = part[1023];
}

__global__ __launch_bounds__(256) void k_fill(const int* __restrict__ ei,
                                              const float* __restrict__ ew,
                                              const float* __restrict__ dinv,
                                              int* __restrict__ cursor,
                                              int* __restrict__ csrc,
                                              float* __restrict__ cnorm) {
  int g = blockIdx.x * 256 + threadIdx.x;
  if (g < EDGES) {
    int s = ei[g], d = ei[EDGES + g];
    int slot = atomicAdd(&cursor[d], 1);
    csrc[slot]  = s;
    cnorm[slot] = dinv[s] * ew[g] * dinv[d];
  }
}

// fill pad slots (cursor[n]..rp[n+1]) with src=0, w=0
__global__ __launch_bounds__(256) void k_padfill(const int* __restrict__ rp,
                                                 const int* __restrict__ cursor,
                                                 int* __restrict__ csrc,
                                                 float* __restrict__ cnorm) {
  int n = blockIdx.x * 256 + threadIdx.x;
  if (n >= N_NODES) return;
  int e = cursor[n], e1 = rp[n + 1];
  for (; e < e1; e++) { csrc[e] = 0; cnorm[e] = 0.0f; }
}

// pack conv weights:
//  p1c [192][128]: row kk: t3=kk>>6, i=kk&63; col: half=col>>6 (t'=10+half), o=col&63
//  p2c [128][64]:  row kk: g=kk>>6 (t1 half), i=kk&63
//  pb1 [128] = tc1_b duplicated
__global__ __launch_bounds__(256) void k_pack(const float* __restrict__ tc1w,
                                              const float* __restrict__ tc2w,
                                              const float* __restrict__ tc1b,
                                              float* __restrict__ p1c,
                                              float* __restrict__ p2c,
                                              float* __restrict__ pb1) {
  int g = blockIdx.x * 256 + threadIdx.x;
  if (g < 24576) {
    int kk = g >> 7, col = g & 127;
    int t3 = kk >> 6, i = kk & 63;
    int half = col >> 6, o = col & 63;
    float v;
    if (half == 0) v = tc1w[o * 192 + i * 3 + t3];
    else           v = (t3 == 0) ? 0.0f : tc1w[o * 192 + i * 3 + (t3 - 1)];
    p1c[g] = v;
  } else if (g < 24576 + 8192) {
    int r = g - 24576;
    int kk = r >> 6, o = r & 63;
    int gk = kk >> 6, i = kk & 63;
    p2c[r] = tc2w[o * 192 + i * 3 + gk];
  } else if (g < 24576 + 8192 + 128) {
    int r = g - 24576 - 8192;
    pb1[r] = tc1b[r & 63];
  }
}

// ---------------- GCN layer 1: fused agg(X) @ W1 + b1, relu -> h1[b][n][t3*64+c] ----------------

__global__ __launch_bounds__(256) void k_aggg1(const float* __restrict__ X,
                                               const float* __restrict__ dinv,
                                               const int* __restrict__ rp,
                                               const int* __restrict__ csrc,
                                               const float* __restrict__ cnorm,
                                               const float* __restrict__ W1,
                                               const float* __restrict__ b1,
                                               float* __restrict__ h1) {
  int b = blockIdx.x & 7;                    // batch -> XCD affinity
  int grp = blockIdx.x >> 3;                 // 0..2499
  int n = grp * 4 + (threadIdx.x >> 6);
  int lane = threadIdx.x & 63;
  const float2* x0 = (const float2*)(X + (size_t)(b * TT + 9)  * N_NODES * 2);
  const float2* x1 = (const float2*)(X + (size_t)(b * TT + 10) * N_NODES * 2);
  const float2* x2 = (const float2*)(X + (size_t)(b * TT + 11) * N_NODES * 2);
  float a0x = 0.f, a0y = 0.f, a1x = 0.f, a1y = 0.f, a2x = 0.f, a2y = 0.f;
  int e0 = rp[n], e1 = rp[n + 1];
  for (int idx = e0 + lane; idx < e1; idx += 64) {
    float w = cnorm[idx];
    int s = csrc[idx];
    float2 s0 = x0[s], s1 = x1[s], s2v = x2[s];
    a0x += w * s0.x;  a0y += w * s0.y;
    a1x += w * s1.x;  a1y += w * s1.y;
    a2x += w * s2v.x; a2y += w * s2v.y;
  }
  if (lane == 0) {  // self-loop term
    float di = dinv[n];
    float sd = di * di;
    float2 v0 = x0[n], v1 = x1[n], v2 = x2[n];
    a0x += sd * v0.x; a0y += sd * v0.y;
    a1x += sd * v1.x; a1y += sd * v1.y;
    a2x += sd * v2.x; a2y += sd * v2.y;
  }
  #pragma unroll
  for (int off = 32; off > 0; off >>= 1) {
    a0x += __shfl_xor(a0x, off, 64);
    a0y += __shfl_xor(a0y, off, 64);
    a1x += __shfl_xor(a1x, off, 64);
    a1y += __shfl_xor(a1y, off, 64);
    a2x += __shfl_xor(a2x, off, 64);
    a2y += __shfl_xor(a2y, off, 64);
  }
  int c = lane;
  float w0 = W1[c], w1 = W1[64 + c], bc = b1[c];
  size_t ob = ((size_t)(b * N_NODES + n)) * 192 + c;
  h1[ob]       = fmaxf(a0x * w0 + a0y * w1 + bc, 0.0f);
  h1[ob + 64]  = fmaxf(a1x * w0 + a1y * w1 + bc, 0.0f);
  h1[ob + 128] = fmaxf(a2x * w0 + a2y * w1 + bc, 0.0f);
}

// ---------------- GCN layer 2 aggregation: t3-sliced (L2-resident) + 4-edge float4 groups ----
__global__ __launch_bounds__(256) void k_agg1t4(const float* __restrict__ h1,
                                                const float* __restrict__ dinv,
                                                const int* __restrict__ rp,
                                                const int* __restrict__ csrc,
                                                const float* __restrict__ cnorm,
                                                float* __restrict__ ah) {
  int b = blockIdx.x & 7;
  int r = blockIdx.x >> 3;                   // 0..7499
  int t3 = r / 2500;
  int grp = r % 2500;
  int n = grp * 4 + (threadIdx.x >> 6);
  int lane = threadIdx.x & 63;
  int sub = lane >> 4;
  int q = lane & 15;
  const char* plane = (const char*)(h1 + (size_t)b * N_NODES * 192 + t3 * 64);
  int qoff = q * 16;
  float ax = 0.f, ay = 0.f, az = 0.f, aw = 0.f;
  int e0 = rp[n], e1 = rp[n + 1];
  for (int base = e0; base < e1; base += 64) {
    int idx = base + lane;
    int ic = (idx < e1) ? idx : e0;
    int   sv = csrc[ic];
    int   wv = ((const int*)cnorm)[ic];
    int m = e1 - base; if (m > 64) m = 64;   // multiple of 8
    int perm = sub * 4;                      // byte addr of source lane (4g+sub)
    int ng = m >> 2;                         // even
    #pragma unroll 2
    for (int g2 = 0; g2 < ng; g2++) {
      int   sj = __builtin_amdgcn_ds_bpermute(perm, sv);
      float wj = __int_as_float(__builtin_amdgcn_ds_bpermute(perm, wv));
      int voff = __mul24(sj, 768) + qoff;
      float4 hv = *(const float4*)(plane + voff);
      ax += wj * hv.x;
      ay += wj * hv.y;
      az += wj * hv.z;
      aw += wj * hv.w;
      perm += 16;
    }
  }
  // reduce across the 4 sub-groups
  ax += __shfl_xor(ax, 16, 64); ay += __shfl_xor(ay, 16, 64);
  az += __shfl_xor(az, 16, 64); aw += __shfl_xor(aw, 16, 64);
  ax += __shfl_xor(ax, 32, 64); ay += __shfl_xor(ay, 32, 64);
  az += __shfl_xor(az, 32, 64); aw += __shfl_xor(aw, 32, 64);
  if (sub == 0) {
    float di = dinv[n];
    float s2 = di * di;
    float4 self = *(const float4*)(plane + __mul24(n, 768) + qoff);
    float4 o;
    o.x = ax + s2 * self.x;
    o.y = ay + s2 * self.y;
    o.z = az + s2 * self.z;
    o.w = aw + s2 * self.w;
    *(float4*)((char*)ah + (((size_t)(b * N_NODES + n)) * 192 + t3 * 64) * 4 + qoff) = o;
  }
}

// ---------------- fused epilogue v2: W2-GEMM + conv1 + conv2 + out, per 32-node block -------
// LDS 50,176 B -> 3 blocks/CU (12 waves). Row-major [m][k] tiles with strides 36/196/132;
// all inner-loop LDS reads are float4 along k (b128), A-fragment reads are 2-4-address
// wave broadcasts -> no bank conflicts in the hot loops.
__global__ __launch_bounds__(256, 3) void k_fused(const float* __restrict__ ah,
                                                  const float* __restrict__ W2,
                                                  const float* __restrict__ b2,
                                                  const float* __restrict__ p1c,
                                                  const float* __restrict__ pb1,
                                                  const float* __restrict__ p2c,
                                                  const float* __restrict__ tc2b,
                                                  const float* __restrict__ ow,
                                                  const float* __restrict__ obp,
                                                  float* __restrict__ out) {
  __shared__ __align__(16) float smem[12544];    // 50,176 B
  float* spL = smem;                             // [32][196] = 6272
  float* ovl = smem + 6272;                      // As [96][36]=3456  |  t1L [32][132]=4224
  float* Ws  = smem + 6272 + 4224;               // 2048 floats (8 KB), shared chunk buffer
  float* As  = ovl;
  float* t1L = ovl;
  int tid = threadIdx.x;
  size_t nodeBase = (size_t)blockIdx.x * 32;     // in (b*N+n) units
  const float* A = ah + nodeBase * 192;          // 96 rows (n,t3) x 64, row-major

  // ---- phase 1: sp = relu(A[96x64] @ W2[64x64] + b2) -> spL[n][t3*64+c]
  {
    int ty = tid >> 4, tx = tid & 15;            // rows 6ty+i, cols 4tx+j
    float acc[6][4] = {{0.f}};
    for (int k0 = 0; k0 < 64; k0 += 32) {
      #pragma unroll
      for (int rep = 0; rep < 3; rep++) {        // As: 768 float4
        int idx = rep * 256 + tid;
        int m = idx >> 3, q4 = (idx & 7) * 4;
        *(float4*)&As[m * 36 + q4] = *(const float4*)(A + m * 64 + k0 + q4);
      }
      #pragma unroll
      for (int rep = 0; rep < 2; rep++) {        // Ws: [32][64] chunk of W2
        int idx = rep * 256 + tid;
        int kk = idx >> 4, c4 = (idx & 15) * 4;
        *(float4*)&Ws[kk * 64 + c4] = *(const float4*)(W2 + (size_t)(k0 + kk) * 64 + c4);
      }
      __syncthreads();
      #pragma unroll
      for (int k = 0; k < 32; k += 4) {
        float4 a[6], w[4];
        #pragma unroll
        for (int i = 0; i < 6; i++) a[i] = *(const float4*)&As[(6 * ty + i) * 36 + k];
        #pragma unroll
        for (int kk = 0; kk < 4; kk++) w[kk] = *(const float4*)&Ws[(k + kk) * 64 + 4 * tx];
        #pragma unroll
        for (int i = 0; i < 6; i++) {
          float av[4] = {a[i].x, a[i].y, a[i].z, a[i].w};
          #pragma unroll
          for (int kk = 0; kk < 4; kk++) {
            acc[i][0] += av[kk] * w[kk].x;
            acc[i][1] += av[kk] * w[kk].y;
            acc[i][2] += av[kk] * w[kk].z;
            acc[i][3] += av[kk] * w[kk].w;
          }
        }
      }
      __syncthreads();
    }
    float4 bv = *(const float4*)(b2 + 4 * tx);
    #pragma unroll
    for (int i = 0; i < 6; i++) {
      int m = 6 * ty + i;
      int n = m / 3, t3 = m % 3;
      float4 o;
      o.x = fmaxf(acc[i][0] + bv.x, 0.0f);
      o.y = fmaxf(acc[i][1] + bv.y, 0.0f);
      o.z = fmaxf(acc[i][2] + bv.z, 0.0f);
      o.w = fmaxf(acc[i][3] + bv.w, 0.0f);
      *(float4*)&spL[n * 196 + t3 * 64 + 4 * tx] = o;
    }
  }
  __syncthreads();

  // ---- phase 2: t1 = relu(spL[32x192] @ p1c[192x128] + pb1) -> t1L[32][132]
  {
    int ty = tid >> 5, tx = tid & 31;            // rows 4ty+i, cols 4tx+j
    float acc[4][4] = {{0.f}};
    for (int c12 = 0; c12 < 12; c12++) {
      #pragma unroll
      for (int rep = 0; rep < 2; rep++) {        // Ws: [16][128] chunk of p1c
        int idx = rep * 256 + tid;
        int kk = idx >> 5, c4 = (idx & 31) * 4;
        *(float4*)&Ws[kk * 128 + c4] = *(const float4*)(p1c + (size_t)(c12 * 16 + kk) * 128 + c4);
      }
      __syncthreads();
      int kbase = c12 * 16;
      #pragma unroll
      for (int k = 0; k < 16; k += 4) {
        float4 a[4], w[4];
        #pragma unroll
        for (int i = 0; i < 4; i++) a[i] = *(const float4*)&spL[(4 * ty + i) * 196 + kbase + k];
        #pragma unroll
        for (int kk = 0; kk < 4; kk++) w[kk] = *(const float4*)&Ws[(k + kk) * 128 + 4 * tx];
        #pragma unroll
        for (int i = 0; i < 4; i++) {
          float av[4] = {a[i].x, a[i].y, a[i].z, a[i].w};
          #pragma unroll
          for (int kk = 0; kk < 4; kk++) {
            acc[i][0] += av[kk] * w[kk].x;
            acc[i][1] += av[kk] * w[kk].y;
            acc[i][2] += av[kk] * w[kk].z;
            acc[i][3] += av[kk] * w[kk].w;
          }
        }
      }
      __syncthreads();
    }
    float4 bv = *(const float4*)(pb1 + 4 * tx);
    #pragma unroll
    for (int i = 0; i < 4; i++) {
      float4 o;
      o.x = fmaxf(acc[i][0] + bv.x, 0.0f);
      o.y = fmaxf(acc[i][1] + bv.y, 0.0f);
      o.z = fmaxf(acc[i][2] + bv.z, 0.0f);
      o.w = fmaxf(acc[i][3] + bv.w, 0.0f);
      *(float4*)&t1L[(4 * ty + i) * 132 + 4 * tx] = o;
    }
  }
  __syncthreads();

  // ---- phase 3: last = relu(t1L[32x128] @ p2c[128x64] + tc2b); out = last . ow + ob
  {
    int ty = tid >> 4, tx = tid & 15;            // rows 2ty+i, cols 4tx+j
    float acc[2][4] = {{0.f}};
    for (int c8 = 0; c8 < 8; c8++) {
      {                                          // Ws: [16][64] chunk of p2c
        int kk = tid >> 4, c4 = (tid & 15) * 4;
        *(float4*)&Ws[kk * 64 + c4] = *(const float4*)(p2c + (size_t)(c8 * 16 + kk) * 64 + c4);
      }
      __syncthreads();
      int kbase = c8 * 16;
      #pragma unroll
      for (int k = 0; k < 16; k += 4) {
        float4 a[2], w[4];
        #pragma unroll
        for (int i = 0; i < 2; i++) a[i] = *(const float4*)&t1L[(2 * ty + i) * 132 + kbase + k];
        #pragma unroll
        for (int kk = 0; kk < 4; kk++) w[kk] = *(const float4*)&Ws[(k + kk) * 64 + 4 * tx];
        #pragma unroll
        for (int i = 0; i < 2; i++) {
          float av[4] = {a[i].x, a[i].y, a[i].z, a[i].w};
          #pragma unroll
          for (int kk = 0; kk < 4; kk++) {
            acc[i][0] += av[kk] * w[kk].x;
            acc[i][1] += av[kk] * w[kk].y;
            acc[i][2] += av[kk] * w[kk].z;
            acc[i][3] += av[kk] * w[kk].w;
          }
        }
      }
      __syncthreads();
    }
    float4 bv = *(const float4*)(tc2b + 4 * tx);
    float4 o4 = *(const float4*)(ow + 4 * tx);
    float obv = obp[0];
    #pragma unroll
    for (int i = 0; i < 2; i++) {
      float v = fmaxf(acc[i][0] + bv.x, 0.0f) * o4.x
              + fmaxf(acc[i][1] + bv.y, 0.0f) * o4.y
              + fmaxf(acc[i][2] + bv.z, 0.0f) * o4.z
              + fmaxf(acc[i][3] + bv.w, 0.0f) * o4.w;
      v += __shfl_xor(v, 1, 64);
      v += __shfl_xor(v, 2, 64);
      v += __shfl_xor(v, 4, 64);
      v += __shfl_xor(v, 8, 64);
      if (tx == 0) out[nodeBase + 2 * ty + i] = v + obv;
    }
  }
}

// ---------------- launch ----------------

extern "C" void kernel_launch(void* const* d_in, const int* in_sizes, int n_in,
                              void* d_out, int out_size, void* d_ws, size_t ws_size,
                              hipStream_t stream) {
  const float* X    = (const float*)d_in[0];
  const int*   EI   = (const int*)  d_in[1];
  const float* EW   = (const float*)d_in[2];
  const float* W1   = (const float*)d_in[3];
  const float* B1   = (const float*)d_in[4];
  const float* W2   = (const float*)d_in[5];
  const float* B2   = (const float*)d_in[6];
  const float* TC1W = (const float*)d_in[7];
  const float* TC1B = (const float*)d_in[8];
  const float* TC2W = (const float*)d_in[9];
  const float* TC2B = (const float*)d_in[10];
  const float* OW   = (const float*)d_in[11];
  const float* OB   = (const float*)d_in[12];
  float* out = (float*)d_out;

  char* base = (char*)d_ws;
  size_t off = 0;
  auto alloc = [&](size_t bytes) -> char* {
    char* p = base + off;
    off += (bytes + 255) & ~(size_t)255;
    return p;
  };
  float* deg   = (float*)alloc(N_NODES * 4);
  float* dinv  = (float*)alloc(N_NODES * 4);
  int*   cnt   = (int*)  alloc(N_NODES * 4);
  int*   rp    = (int*)  alloc((N_NODES + 1) * 4);
  int*   cur   = (int*)  alloc(N_NODES * 4);
  int*   csrc  = (int*)  alloc(EPAD * 4);
  float* cnorm = (float*)alloc(EPAD * 4);
  float* p1c   = (float*)alloc(192 * 128 * 4);
  float* p2c   = (float*)alloc(128 * 64 * 4);
  float* pb1   = (float*)alloc(128 * 4);
  const size_t BIG = (size_t)80000 * 192;
  float* h1 = (float*)alloc(BIG * 4);
  float* ah = (float*)alloc(BIG * 4);

  hipMemsetAsync(deg, 0, N_NODES * 4, stream);
  hipMemsetAsync(cnt, 0, N_NODES * 4, stream);
  k_deg_hist<<<625, 256, 0, stream>>>(EI, EW, deg, cnt);
  k_dinv<<<40, 256, 0, stream>>>(deg, dinv);
  k_scan<<<1, 1024, 0, stream>>>(cnt, rp, cur);
  k_fill<<<625, 256, 0, stream>>>(EI, EW, dinv, cur, csrc, cnorm);
  k_padfill<<<40, 256, 0, stream>>>(rp, cur, csrc, cnorm);
  k_pack<<<129, 256, 0, stream>>>(TC1W, TC2W, TC1B, p1c, p2c, pb1);

  // layer 1 (agg + W1 + relu), t=9..11 fused
  k_aggg1<<<20000, 256, 0, stream>>>(X, dinv, rp, csrc, cnorm, W1, B1, h1);
  // layer 2 aggregation, t3-sliced, 4-edge vector gather
  k_agg1t4<<<60000, 256, 0, stream>>>(h1, dinv, rp, csrc, cnorm, ah);
  // fused W2-GEMM + conv1 + conv2 + out (32 nodes/block)
  k_fused<<<2500, 256, 0, stream>>>(ah, W2, B2, p1c, pb1, p2c, TC2B, OW, OB, out);
}